// Round 10
// baseline (3882.952 us; speedup 1.0000x reference)
//
#include <hip/hip_runtime.h>

#define HW_ (512 * 512)
#define B_ 8
#define H_ 512
#define W_ 512
#define K_ 32
#define CH_ 16
#define CHPIX_ (HW_ / CH_)  // 16384 pixels per chunk

typedef float float2v __attribute__((ext_vector_type(2)));

// ---------------- compact phase A: per-chunk valid count ----------------
__global__ void k_count(const float* __restrict__ seg, int* __restrict__ chunkCnt) {
  const int blk = blockIdx.x;  // b*CH_ + c
  const int t = threadIdx.x;
  const float4* __restrict__ s4 = (const float4*)(seg + (size_t)blk * CHPIX_) + (size_t)t * 16;
  int cnt = 0;
#pragma unroll
  for (int j = 0; j < 16; ++j) {
    float4 v = s4[j];
    cnt += (v.x >= 0.9f) + (v.y >= 0.9f) + (v.z >= 0.9f) + (v.w >= 0.9f);
  }
  __shared__ int red[256];
  red[t] = cnt;
  __syncthreads();
  for (int off = 128; off > 0; off >>= 1) {
    if (t < off) red[t] += red[t + off];
    __syncthreads();
  }
  if (t == 0) chunkCnt[blk] = red[0];
}

// ---------------- compact phase B: per-batch chunk base offsets ----------------
__global__ void k_scan(const int* __restrict__ chunkCnt, int* __restrict__ chunkBase,
                       int* __restrict__ nvalid, int cap) {
  const int t = threadIdx.x;  // b*CH_ + c
  if (t < B_ * CH_) {
    const int b = t / CH_, c = t % CH_;
    int base = 0;
    for (int q = 0; q < c; ++q) base += chunkCnt[b * CH_ + q];
    chunkBase[t] = base;
    if (c == CH_ - 1) nvalid[b] = min(base + chunkCnt[t], cap);
  }
}

// ---------------- compact phase C: ordered compaction + gather + lanes memset ----------------
__global__ void k_fill(const float* __restrict__ seg, const float* __restrict__ emb,
                       const int* __restrict__ chunkBase, unsigned char* __restrict__ lanes,
                       int* __restrict__ idxC, float* __restrict__ embC, int cap) {
  const int blk = blockIdx.x;  // b*CH_ + c
  const int b = blk / CH_;
  const int t = threadIdx.x;
  const size_t pixbase = (size_t)blk * CHPIX_ + (size_t)t * 64;
  const float4* __restrict__ s4 = (const float4*)(seg + pixbase);

  int cnt = 0;
#pragma unroll
  for (int j = 0; j < 16; ++j) {
    float4 v = s4[j];
    cnt += (v.x >= 0.9f) + (v.y >= 0.9f) + (v.z >= 0.9f) + (v.w >= 0.9f);
  }
  __shared__ int pre[256];
  pre[t] = cnt;
  __syncthreads();
  for (int off = 1; off < 256; off <<= 1) {
    int mine = pre[t];
    int add = (t >= off) ? pre[t - off] : 0;
    __syncthreads();
    pre[t] = mine + add;
    __syncthreads();
  }
  int w = chunkBase[blk] + pre[t] - cnt;

  uint4 z = {0u, 0u, 0u, 0u};
  uint4* lz = (uint4*)(lanes + pixbase);
  lz[0] = z; lz[1] = z; lz[2] = z; lz[3] = z;

  const float* __restrict__ eb = emb + (size_t)b * 8 * HW_;
  const int pixInB = (int)(pixbase - (size_t)b * HW_);
  for (int j = 0; j < 16; ++j) {
    float4 v = s4[j];
    float sv[4] = {v.x, v.y, v.z, v.w};
#pragma unroll
    for (int q = 0; q < 4; ++q) {
      if (sv[q] >= 0.9f && w < cap) {
        const int p = pixInB + j * 4 + q;
        idxC[(size_t)b * cap + w] = p;
        float* dst = embC + ((size_t)b * cap + w) * 8;
#pragma unroll
        for (int dd = 0; dd < 8; ++dd) dst[dd] = eb[(size_t)dd * HW_ + p];
        ++w;
      }
    }
  }
}

// ---------------- sequential clustering: spec-dsq pipeline + packed f32 ----------------
// 8 blocks x 1 wave, one batch each. Centers on lanes 0-31 (32-63 mirror).
// ON-CHAIN per step: dsq = fma(wp, fma(wp, dsqq, m2g), dspec) -> key -> 4x
// v_min_u32_dpp (inline asm) -> 2 readlane -> SALU decide -> w.
// OFF-CHAIN (packed float2 / v_pk_fma_f32): C update, t correction, next tspec,
// |tspec|^2 tree, g dot. Identity (exact algebra, validated round 9):
//   |e_{j+1}-C_{j+1}|^2 = |s|^2 - 2 w (t_j . s) + w^2 |t_j|^2,  s = e_{j+1}-C_j.

#define TILE_ 64

__device__ __forceinline__ void stage16(const float* g, float* l) {
  __builtin_amdgcn_global_load_lds(
      (const __attribute__((address_space(1))) void*)g,
      (__attribute__((address_space(3))) void*)l, 16, 0, 0);
}

#define RLF(V, L) __uint_as_float((unsigned)__builtin_amdgcn_readlane(__float_as_int(V), (L)))
#define RLU(V, L) ((unsigned)__builtin_amdgcn_readlane((int)(V), (L)))
#define PKF(A, B, C) __builtin_elementwise_fma((A), (B), (C))

// PK: pack register; SH: byte slot 0..7; TD: float4 with pixel (j+1)'s halves;
// L: lane of the low half (even).
#define STEPX(PK, SH, TD, L)                                                     \
  do {                                                                           \
    /* on-chain: corrected dsq for pixel j */                                    \
    float dsq = __builtin_fmaf(wp2.x, __builtin_fmaf(wp2.x, dsqq, m2g), dspec);  \
    unsigned db = __float_as_uint(dsq);                                          \
    unsigned dbm = db > emptyBits ? db : emptyBits; /* empty center -> inf */    \
    unsigned mn = (dbm & 0xFFFFFFE0u) | (unsigned)cl;                            \
    asm volatile(                                                                \
        "s_nop 1\n\t"                                                            \
        "v_min_u32_dpp %0, %0, %0 quad_perm:[1,0,3,2] row_mask:0xf bank_mask:0xf\n\t" \
        "s_nop 1\n\t"                                                            \
        "v_min_u32_dpp %0, %0, %0 quad_perm:[2,3,0,1] row_mask:0xf bank_mask:0xf\n\t" \
        "s_nop 1\n\t"                                                            \
        "v_min_u32_dpp %0, %0, %0 row_half_mirror row_mask:0xf bank_mask:0xf\n\t" \
        "s_nop 1\n\t"                                                            \
        "v_min_u32_dpp %0, %0, %0 row_mirror row_mask:0xf bank_mask:0xf\n\t"     \
        "s_nop 1"                                                                \
        : "+v"(mn));                                                             \
    unsigned q0 = RLU(mn, 0), q1 = RLU(mn, 16);                                  \
    unsigned mv = q0 < q1 ? q0 : q1; /* uniform -> SALU */                       \
    bool join = mv < 0x41100000u;    /* dsq < 9.0 <=> sqrt(dsq) < 3 */           \
    int cid = join ? (int)(mv & 31u) : (nact < 31 ? nact : 31);                  \
    nact += join ? 0 : 1;                                                        \
    bool own = (cl == cid);                                                      \
    float wj = join ? inv : 1.0f;                                                \
    float w = own ? wj : 0.0f;                                                   \
    /* off-chain (packed): apply PREVIOUS update, correct t_j */                 \
    C01 = PKF(wp2, t01, C01); C23 = PKF(wp2, t23, C23);                          \
    C45 = PKF(wp2, t45, C45); C67 = PKF(wp2, t67, C67);                          \
    t01 = PKF(-wp2, t01, s01); t23 = PKF(-wp2, t23, s23);                        \
    t45 = PKF(-wp2, t45, s45); t67 = PKF(-wp2, t67, s67);                        \
    /* e_{j+1} broadcast, spec tspec / |tspec|^2 / g */                          \
    float2v e01, e23, e45, e67;                                                  \
    e01.x = RLF((TD).x, (L)); e01.y = RLF((TD).y, (L));                          \
    e23.x = RLF((TD).z, (L)); e23.y = RLF((TD).w, (L));                          \
    e45.x = RLF((TD).x, (L) + 1); e45.y = RLF((TD).y, (L) + 1);                  \
    e67.x = RLF((TD).z, (L) + 1); e67.y = RLF((TD).w, (L) + 1);                  \
    s01 = e01 - C01; s23 = e23 - C23; s45 = e45 - C45; s67 = e67 - C67;          \
    float2v p = s01 * s01;                                                       \
    p = PKF(s23, s23, p);                                                        \
    float2v p2 = s45 * s45;                                                      \
    p2 = PKF(s67, s67, p2);                                                      \
    p = p + p2;                                                                  \
    dspec = p.x + p.y;                                                           \
    float2v gv = t01 * s01;                                                      \
    gv = PKF(t23, s23, gv);                                                      \
    float2v gv2 = t45 * s45;                                                     \
    gv2 = PKF(t67, s67, gv2);                                                    \
    gv = gv + gv2;                                                               \
    m2g = -2.0f * (gv.x + gv.y);                                                 \
    dsqq = dsq;                                                                  \
    wp2.x = w; wp2.y = w;                                                        \
    cnt += own ? 1.0f : 0.0f;                                                    \
    inv = __builtin_amdgcn_rcpf(cnt + 1.0f); /* used next step */                \
    emptyBits = own ? 0u : emptyBits;                                            \
    PK |= (unsigned long long)(unsigned)(cid + 1) << ((SH) * 8);                 \
  } while (0)

__global__ __launch_bounds__(64, 1) void k_cluster(const float* __restrict__ embC,
                                                   const int* __restrict__ nvalid,
                                                   unsigned char* __restrict__ cidArr,
                                                   int cap) {
  __shared__ float lds[1024];  // 2 phases x 512 floats (2KB per phase)
  const int b = blockIdx.x;
  const int lane = threadIdx.x;
  const int cl = lane & 31;
  const int n = nvalid[b];
  if (n <= 0) return;
  const int nTiles = (n + TILE_ - 1) / TILE_;

  const float* src = embC + (size_t)b * cap * 8 + lane * 4;
  unsigned char* cidB = cidArr + (size_t)b * HW_;
  const float4* f4 = (const float4*)lds;

  float2v C01 = {0.f, 0.f}, C23 = C01, C45 = C01, C67 = C01;
  float2v t01 = C01, t23 = C01, t45 = C01, t67 = C01;
  float2v s01, s23, s45, s67;
  float2v wp2 = {0.f, 0.f};
  float cnt = 0.f, inv = 1.0f, m2g = 0.f, dsqq = 0.f, dspec;
  unsigned emptyBits = 0x7F800000u;
  int nact = 0;
  unsigned long long pk0 = 0, pk1 = 0, pk2 = 0, pk3 = 0, pk4 = 0, pk5 = 0, pk6 = 0, pk7 = 0;

  // prologue: stage tile 0 (2KB), wait, pull my 2x16B into registers
  stage16(src, lds);
  stage16(src + 256, lds + 256);
  asm volatile("s_waitcnt vmcnt(0)" ::: "memory");
  __builtin_amdgcn_sched_barrier(0);
  float4 td = f4[lane], td2 = f4[64 + lane];
  float4 tdN = td, td2N = td2;

  // pipeline init: tspec for pixel 0 against C=0 (s = e_0), dspec = |e_0|^2
  s01.x = RLF(td.x, 0); s01.y = RLF(td.y, 0);
  s23.x = RLF(td.z, 0); s23.y = RLF(td.w, 0);
  s45.x = RLF(td.x, 1); s45.y = RLF(td.y, 1);
  s67.x = RLF(td.z, 1); s67.y = RLF(td.w, 1);
  {
    float2v p = s01 * s01;
    p = PKF(s23, s23, p);
    float2v p2 = s45 * s45;
    p2 = PKF(s67, s67, p2);
    p = p + p2;
    dspec = p.x + p.y;
  }

  // step s (pixel s of tile): pack -> pk[s>>3] slot (s&7); e source = pixel s+1:
  // p = s+1 in 1..31 -> td lane 2p; 32..63 -> td2 lane 2(p-32); 64 -> tdN lane 0.
#define ROW8(PK, TDa, La, TDb, Lb, TDc, Lc, TDd, Ld, TDe, Le, TDf, Lf, TDg, Lg, TDh, Lh) \
  STEPX(PK, 0, TDa, La); STEPX(PK, 1, TDb, Lb); STEPX(PK, 2, TDc, Lc); STEPX(PK, 3, TDd, Ld); \
  STEPX(PK, 4, TDe, Le); STEPX(PK, 5, TDf, Lf); STEPX(PK, 6, TDg, Lg); STEPX(PK, 7, TDh, Lh);

  for (int ti = 0; ti < nTiles; ++ti) {
    const bool more = (ti + 1 < nTiles);
    if (more) {
      stage16(src + (size_t)(ti + 1) * 512, lds + ((ti + 1) & 1) * 512);
      stage16(src + (size_t)(ti + 1) * 512 + 256, lds + ((ti + 1) & 1) * 512 + 256);
    }
    // steps 0..7   (e: px 1..8)
    ROW8(pk0, td, 2, td, 4, td, 6, td, 8, td, 10, td, 12, td, 14, td, 16)
    // steps 8..15  (e: px 9..16)
    ROW8(pk1, td, 18, td, 20, td, 22, td, 24, td, 26, td, 28, td, 30, td, 32)
    // steps 16..23 (e: px 17..24)
    ROW8(pk2, td, 34, td, 36, td, 38, td, 40, td, 42, td, 44, td, 46, td, 48)
    // steps 24..31 (e: px 25..32; px32 -> td2 lane 0)
    ROW8(pk3, td, 50, td, 52, td, 54, td, 56, td, 58, td, 60, td, 62, td2, 0)
    // steps 32..39 (e: px 33..40)
    ROW8(pk4, td2, 2, td2, 4, td2, 6, td2, 8, td2, 10, td2, 12, td2, 14, td2, 16)
    // steps 40..47 (e: px 41..48)
    ROW8(pk5, td2, 18, td2, 20, td2, 22, td2, 24, td2, 26, td2, 28, td2, 30, td2, 32)

    if (more) {
      // stages for ti+1 issued 48 steps ago -> retired; no newer VMEM ops.
      asm volatile("s_waitcnt vmcnt(0)" ::: "memory");
      __builtin_amdgcn_sched_barrier(0);
      const int ph = ((ti + 1) & 1) * 128;
      tdN = f4[ph + lane];
      td2N = f4[ph + 64 + lane];
    }
    // steps 48..55 (e: px 49..56)
    ROW8(pk6, td2, 34, td2, 36, td2, 38, td2, 40, td2, 42, td2, 44, td2, 46, td2, 48)
    // steps 56..63 (e: px 57..63, then px 0 of next tile)
    ROW8(pk7, td2, 50, td2, 52, td2, 54, td2, 56, td2, 58, td2, 60, td2, 62, tdN, 0)

    if (lane == 0) {
      unsigned char* cptr = cidB + ti * TILE_;
      uint4 v;
      v.x = (unsigned)pk0; v.y = (unsigned)(pk0 >> 32);
      v.z = (unsigned)pk1; v.w = (unsigned)(pk1 >> 32);
      *(uint4*)(cptr + 0) = v;
      v.x = (unsigned)pk2; v.y = (unsigned)(pk2 >> 32);
      v.z = (unsigned)pk3; v.w = (unsigned)(pk3 >> 32);
      *(uint4*)(cptr + 16) = v;
      v.x = (unsigned)pk4; v.y = (unsigned)(pk4 >> 32);
      v.z = (unsigned)pk5; v.w = (unsigned)(pk5 >> 32);
      *(uint4*)(cptr + 32) = v;
      v.x = (unsigned)pk6; v.y = (unsigned)(pk6 >> 32);
      v.z = (unsigned)pk7; v.w = (unsigned)(pk7 >> 32);
      *(uint4*)(cptr + 48) = v;
    }
    pk0 = pk1 = pk2 = pk3 = pk4 = pk5 = pk6 = pk7 = 0ULL;
    td = tdN;
    td2 = td2N;
  }
#undef ROW8
}

// ---------------- scatter cid bytes to the per-pixel lane map ----------------
__global__ void k_scatter(const unsigned char* __restrict__ cidArr,
                          const int* __restrict__ idxC, const int* __restrict__ nvalid,
                          unsigned char* __restrict__ lanes, int cap) {
  const int b = blockIdx.y;
  const int n = nvalid[b];
  for (int j = blockIdx.x * blockDim.x + threadIdx.x; j < n; j += gridDim.x * blockDim.x) {
    lanes[(size_t)b * HW_ + idxC[(size_t)b * cap + j]] = cidArr[(size_t)b * HW_ + j];
  }
}

// ---------------- per-(b,h) segment sums over 33 lane bins ----------------
__global__ void k_rowsum(const unsigned char* __restrict__ lanes,
                         const float* __restrict__ offp, const float* __restrict__ zp,
                         float* __restrict__ cnt, float* __restrict__ sx,
                         float* __restrict__ sz) {
  const int bh = blockIdx.x;
  const int b = bh >> 9, h = bh & 511;
  __shared__ float sc[33], sxx[33], szz[33];
  const int t = threadIdx.x;
  if (t < 33) { sc[t] = 0.f; sxx[t] = 0.f; szz[t] = 0.f; }
  __syncthreads();
  const size_t base = (size_t)bh * W_;
  for (int x = t; x < W_; x += 256) {
    int ln = lanes[base + x];
    float o = offp[base + x];
    float sig = 1.0f / (1.0f + expf(-o));
    float xa = (float)x + sig;
    float zv = zp[base + x];
    atomicAdd(&sc[ln], 1.0f);
    atomicAdd(&sxx[ln], xa);
    atomicAdd(&szz[ln], zv);
  }
  __syncthreads();
  if (t >= 1 && t < 33) {
    size_t o = ((size_t)b * K_ + (t - 1)) * H_ + h;
    cnt[o] = sc[t]; sx[o] = sxx[t]; sz[o] = szz[t];
  }
}

// ---------------- validity + point assembly ----------------
__global__ void k_final(const float* __restrict__ cnt, const float* __restrict__ sx,
                        const float* __restrict__ sz, float* __restrict__ out) {
  const int bk = blockIdx.x;
  const int b = bk >> 5, k = bk & 31;
  const int h = threadIdx.x;
  const size_t o = (size_t)bk * H_ + h;
  float c = cnt[o];
  float sc_ = c, sn = (c > 0.f) ? 1.f : 0.f;
#pragma unroll
  for (int off = 32; off >= 1; off >>= 1) {
    sc_ += __shfl_down(sc_, off);
    sn += __shfl_down(sn, off);
  }
  __shared__ float rs[8], rn[8], tot[2];
  const int wid = h >> 6, lid = h & 63;
  if (lid == 0) { rs[wid] = sc_; rn[wid] = sn; }
  __syncthreads();
  if (h == 0) {
    float a = 0, bb = 0;
#pragma unroll
    for (int q = 0; q < 8; ++q) { a += rs[q]; bb += rn[q]; }
    tot[0] = a; tot[1] = bb;
  }
  __syncthreads();
  float size = tot[0], nrows = tot[1];
  bool valid = (c > 0.f) && (size >= 50.f) && (nrows >= 2.f);
  float mx = sx[o] / fmaxf(c, 1.f);
  float mz = sz[o] / fmaxf(c, 1.f);
  float xw = (512.0f - ((float)h + 0.5f)) * 0.2f;
  float yw = -(mx - 256.0f) * 0.2f;
  out[((size_t)(b * 3 + 0) * K_ + k) * H_ + h] = valid ? xw : 0.f;
  out[((size_t)(b * 3 + 1) * K_ + k) * H_ + h] = valid ? yw : 0.f;
  out[((size_t)(b * 3 + 2) * K_ + k) * H_ + h] = valid ? mz : 0.f;
  out[(size_t)B_ * 3 * K_ * H_ + (size_t)bk * H_ + h] = valid ? 1.f : 0.f;
}

extern "C" void kernel_launch(void* const* d_in, const int* in_sizes, int n_in,
                              void* d_out, int out_size, void* d_ws, size_t ws_size,
                              hipStream_t stream) {
  const float* seg  = (const float*)d_in[0];
  const float* emb  = (const float*)d_in[1];
  const float* offp = (const float*)d_in[2];
  const float* zp   = (const float*)d_in[3];
  float* out = (float*)d_out;
  char* ws = (char*)d_ws;

  const size_t lanesOff = 0;
  const size_t cntOff   = (size_t)B_ * HW_;
  const size_t sxOff    = cntOff + (size_t)B_ * K_ * H_ * 4;
  const size_t szOff    = sxOff  + (size_t)B_ * K_ * H_ * 4;
  const size_t nvOff    = szOff  + (size_t)B_ * K_ * H_ * 4;
  const size_t ccOff    = nvOff + 256;
  const size_t cbOff    = ccOff + 1024;
  const size_t cidOff   = cbOff + 1024;                      // u8 [B][HW_] = 2 MiB
  const size_t idxOff   = cidOff + (size_t)B_ * HW_;
  size_t avail = (ws_size > idxOff + 16384) ? (ws_size - idxOff - 16384) : 0;  // staging slack
  long long capLL = (long long)(avail / ((size_t)B_ * 36));  // 4B idx + 32B emb per entry
  if (capLL > (long long)HW_) capLL = HW_;
  if (capLL < 2) capLL = 2;
  capLL &= ~1LL;  // keep per-batch embC base 64B-aligned
  const int cap = (int)capLL;
  const size_t embOff = idxOff + (size_t)B_ * cap * 4;

  unsigned char* lanes = (unsigned char*)(ws + lanesOff);
  float* cnt = (float*)(ws + cntOff);
  float* sx  = (float*)(ws + sxOff);
  float* sz  = (float*)(ws + szOff);
  int* nvalid = (int*)(ws + nvOff);
  int* chunkCnt  = (int*)(ws + ccOff);
  int* chunkBase = (int*)(ws + cbOff);
  unsigned char* cidArr = (unsigned char*)(ws + cidOff);
  int* idxC   = (int*)(ws + idxOff);
  float* embC = (float*)(ws + embOff);

  k_count<<<B_ * CH_, 256, 0, stream>>>(seg, chunkCnt);
  k_scan<<<1, 128, 0, stream>>>(chunkCnt, chunkBase, nvalid, cap);
  k_fill<<<B_ * CH_, 256, 0, stream>>>(seg, emb, chunkBase, lanes, idxC, embC, cap);
  k_cluster<<<B_, 64, 0, stream>>>(embC, nvalid, cidArr, cap);
  k_scatter<<<dim3(64, B_), 256, 0, stream>>>(cidArr, idxC, nvalid, lanes, cap);
  k_rowsum<<<B_ * H_, 256, 0, stream>>>(lanes, offp, zp, cnt, sx, sz);
  k_final<<<B_ * K_, H_, 0, stream>>>(cnt, sx, sz, out);
}

// Round 11
// 3034.660 us; speedup vs baseline: 1.2795x; 1.2795x over previous
//
#include <hip/hip_runtime.h>

#define HW_ (512 * 512)
#define B_ 8
#define H_ 512
#define W_ 512
#define K_ 32
#define CH_ 16
#define CHPIX_ (HW_ / CH_)  // 16384 pixels per chunk

typedef float float2v __attribute__((ext_vector_type(2)));

// ---------------- compact phase A: per-chunk valid count ----------------
__global__ void k_count(const float* __restrict__ seg, int* __restrict__ chunkCnt) {
  const int blk = blockIdx.x;  // b*CH_ + c
  const int t = threadIdx.x;
  const float4* __restrict__ s4 = (const float4*)(seg + (size_t)blk * CHPIX_) + (size_t)t * 16;
  int cnt = 0;
#pragma unroll
  for (int j = 0; j < 16; ++j) {
    float4 v = s4[j];
    cnt += (v.x >= 0.9f) + (v.y >= 0.9f) + (v.z >= 0.9f) + (v.w >= 0.9f);
  }
  __shared__ int red[256];
  red[t] = cnt;
  __syncthreads();
  for (int off = 128; off > 0; off >>= 1) {
    if (t < off) red[t] += red[t + off];
    __syncthreads();
  }
  if (t == 0) chunkCnt[blk] = red[0];
}

// ---------------- compact phase B: per-batch chunk base offsets ----------------
__global__ void k_scan(const int* __restrict__ chunkCnt, int* __restrict__ chunkBase,
                       int* __restrict__ nvalid, int cap) {
  const int t = threadIdx.x;  // b*CH_ + c
  if (t < B_ * CH_) {
    const int b = t / CH_, c = t % CH_;
    int base = 0;
    for (int q = 0; q < c; ++q) base += chunkCnt[b * CH_ + q];
    chunkBase[t] = base;
    if (c == CH_ - 1) nvalid[b] = min(base + chunkCnt[t], cap);
  }
}

// ---------------- compact phase C: ordered compaction + gather + lanes memset ----------------
__global__ void k_fill(const float* __restrict__ seg, const float* __restrict__ emb,
                       const int* __restrict__ chunkBase, unsigned char* __restrict__ lanes,
                       int* __restrict__ idxC, float* __restrict__ embC, int cap) {
  const int blk = blockIdx.x;  // b*CH_ + c
  const int b = blk / CH_;
  const int t = threadIdx.x;
  const size_t pixbase = (size_t)blk * CHPIX_ + (size_t)t * 64;
  const float4* __restrict__ s4 = (const float4*)(seg + pixbase);

  int cnt = 0;
#pragma unroll
  for (int j = 0; j < 16; ++j) {
    float4 v = s4[j];
    cnt += (v.x >= 0.9f) + (v.y >= 0.9f) + (v.z >= 0.9f) + (v.w >= 0.9f);
  }
  __shared__ int pre[256];
  pre[t] = cnt;
  __syncthreads();
  for (int off = 1; off < 256; off <<= 1) {
    int mine = pre[t];
    int add = (t >= off) ? pre[t - off] : 0;
    __syncthreads();
    pre[t] = mine + add;
    __syncthreads();
  }
  int w = chunkBase[blk] + pre[t] - cnt;

  uint4 z = {0u, 0u, 0u, 0u};
  uint4* lz = (uint4*)(lanes + pixbase);
  lz[0] = z; lz[1] = z; lz[2] = z; lz[3] = z;

  const float* __restrict__ eb = emb + (size_t)b * 8 * HW_;
  const int pixInB = (int)(pixbase - (size_t)b * HW_);
  for (int j = 0; j < 16; ++j) {
    float4 v = s4[j];
    float sv[4] = {v.x, v.y, v.z, v.w};
#pragma unroll
    for (int q = 0; q < 4; ++q) {
      if (sv[q] >= 0.9f && w < cap) {
        const int p = pixInB + j * 4 + q;
        idxC[(size_t)b * cap + w] = p;
        float* dst = embC + ((size_t)b * cap + w) * 8;
#pragma unroll
        for (int dd = 0; dd < 8; ++dd) dst[dd] = eb[(size_t)dd * HW_ + p];
        ++w;
      }
    }
  }
}

// ---------------- sequential clustering: LDS-broadcast e + packed f32 ----------------
// 8 blocks x 1 wave, one batch each. Centers on lanes 0-31 (32-63 mirror).
// e-delivery: 4x ds_read_b64 at a WAVE-UNIFORM address (hardware broadcast,
// conflict-free) with compile-time offsets, issued 2 steps ahead into 3 rotating
// float2 register slots -> LDS pipe, off the VALU and off the chain, and the
// values arrive as natural <2 x float> so the f32 math can select v_pk_* ops.
// Decision path identical to validated round 6: u32 key = (dsq_bits&~31)|cl,
// builtin 4-level DPP min, 2 readlane + SALU min/decide.

#define TILE_ 32

__device__ __forceinline__ void stage16(const float* g, float* l) {
  __builtin_amdgcn_global_load_lds(
      (const __attribute__((address_space(1))) void*)g,
      (__attribute__((address_space(3))) void*)l, 16, 0, 0);
}

#define RLU(V, L) ((unsigned)__builtin_amdgcn_readlane((int)(V), (L)))
#define PKF(A, B, C) __builtin_elementwise_fma((A), (B), (C))

// J: step 0..31 (pixel J of tile). US: slot used = J%3. LS: slot loaded = (J+2)%3.
#define STEPQ(J, US, LS)                                                             \
  do {                                                                               \
    float2v t01 = C01 - e01_##US;                                                    \
    float2v t23 = C23 - e23_##US;                                                    \
    float2v t45 = C45 - e45_##US;                                                    \
    float2v t67 = C67 - e67_##US;                                                    \
    float2v p = t01 * t01;                                                           \
    p = PKF(t23, t23, p);                                                            \
    p = PKF(t45, t45, p);                                                            \
    p = PKF(t67, t67, p);                                                            \
    float dsq = p.x + p.y;                                                           \
    unsigned db = __float_as_uint(dsq);                                              \
    unsigned dbm = db > emptyBits ? db : emptyBits; /* empty center -> inf */        \
    unsigned mn = (dbm & 0xFFFFFFE0u) | (unsigned)cl;                                \
    unsigned mr;                                                                     \
    mr = (unsigned)__builtin_amdgcn_update_dpp(0, (int)mn, 0xB1, 0xF, 0xF, true);    \
    mn = mn < mr ? mn : mr;                                                          \
    mr = (unsigned)__builtin_amdgcn_update_dpp(0, (int)mn, 0x4E, 0xF, 0xF, true);    \
    mn = mn < mr ? mn : mr;                                                          \
    mr = (unsigned)__builtin_amdgcn_update_dpp(0, (int)mn, 0x141, 0xF, 0xF, true);   \
    mn = mn < mr ? mn : mr;                                                          \
    mr = (unsigned)__builtin_amdgcn_update_dpp(0, (int)mn, 0x140, 0xF, 0xF, true);   \
    mn = mn < mr ? mn : mr;                                                          \
    unsigned q0 = RLU(mn, 0), q1 = RLU(mn, 16);                                      \
    unsigned mv = q0 < q1 ? q0 : q1; /* uniform -> SALU */                           \
    bool join = mv < 0x41100000u;    /* dsq < 9.0 <=> sqrt(dsq) < 3, exact */        \
    int cid = join ? (int)(mv & 31u) : (nact < 31 ? nact : 31);                      \
    nact += join ? 0 : 1;                                                            \
    bool own = (cl == cid);                                                          \
    float wj = join ? inv : 1.0f;                                                    \
    float w = own ? wj : 0.0f;                                                       \
    float2v wv = {w, w};                                                             \
    C01 = PKF(t01, -wv, C01); /* C -= w*t */                                         \
    C23 = PKF(t23, -wv, C23);                                                        \
    C45 = PKF(t45, -wv, C45);                                                        \
    C67 = PKF(t67, -wv, C67);                                                        \
    cnt += own ? 1.0f : 0.0f;                                                        \
    inv = __builtin_amdgcn_rcpf(cnt + 1.0f); /* off-chain: used next step */         \
    emptyBits = own ? 0u : emptyBits;                                                \
    pk |= (unsigned long long)(unsigned)(cid + 1) << (((J) & 7) * 8);                \
    if (((J) & 7) == 7) {                                                            \
      if (lane == 0) *(unsigned long long*)(cptr + ((J) & ~7)) = pk;                 \
      pk = 0ULL;                                                                     \
    }                                                                                \
    if ((J) < TILE_ - 2) { /* issue e-loads for step J+2 (uniform broadcast) */      \
      e01_##LS = ebq[((J) + 2) * 4 + 0];                                             \
      e23_##LS = ebq[((J) + 2) * 4 + 1];                                             \
      e45_##LS = ebq[((J) + 2) * 4 + 2];                                             \
      e67_##LS = ebq[((J) + 2) * 4 + 3];                                             \
    }                                                                                \
  } while (0)

__global__ __launch_bounds__(64, 1) void k_cluster(const float* __restrict__ embC,
                                                   const int* __restrict__ nvalid,
                                                   unsigned char* __restrict__ cidArr,
                                                   int cap) {
  __shared__ float lds[512];  // 2 phases x 256 floats (1KB per phase)
  const int b = blockIdx.x;
  const int lane = threadIdx.x;
  const int cl = lane & 31;
  const int n = nvalid[b];
  if (n <= 0) return;
  const int nTiles = (n + TILE_ - 1) / TILE_;

  const float* src = embC + (size_t)b * cap * 8 + lane * 4;
  unsigned char* cidB = cidArr + (size_t)b * HW_;

  float2v C01 = {0.f, 0.f}, C23 = C01, C45 = C01, C67 = C01;
  float2v e01_0, e23_0, e45_0, e67_0;
  float2v e01_1, e23_1, e45_1, e67_1;
  float2v e01_2, e23_2, e45_2, e67_2;
  float cnt = 0.f, inv = 1.0f;
  unsigned emptyBits = 0x7F800000u;
  int nact = 0;
  unsigned long long pk = 0ULL;

  // prologue: stage tile 0 into phase 0, wait
  stage16(src, lds);
  asm volatile("s_waitcnt vmcnt(0)" ::: "memory");
  __builtin_amdgcn_sched_barrier(0);

  for (int ti = 0; ti < nTiles; ++ti) {
    const bool more = (ti + 1 < nTiles);
    const float2v* ebq = (const float2v*)((const char*)lds + (ti & 1) * 1024);
    unsigned char* cptr = cidB + ti * TILE_;

    // slot prologue: pixels 0,1 of this tile (uniform-broadcast LDS reads)
    e01_0 = ebq[0]; e23_0 = ebq[1]; e45_0 = ebq[2]; e67_0 = ebq[3];
    e01_1 = ebq[4]; e23_1 = ebq[5]; e45_1 = ebq[6]; e67_1 = ebq[7];

    if (more)  // stage next tile into the other phase
      stage16(src + (size_t)(ti + 1) * 256, lds + ((ti + 1) & 1) * 256);

    STEPQ(0, 0, 2);  STEPQ(1, 1, 0);  STEPQ(2, 2, 1);  STEPQ(3, 0, 2);
    STEPQ(4, 1, 0);  STEPQ(5, 2, 1);  STEPQ(6, 0, 2);  STEPQ(7, 1, 0);
    STEPQ(8, 2, 1);  STEPQ(9, 0, 2);  STEPQ(10, 1, 0); STEPQ(11, 2, 1);
    STEPQ(12, 0, 2); STEPQ(13, 1, 0); STEPQ(14, 2, 1); STEPQ(15, 0, 2);
    STEPQ(16, 1, 0); STEPQ(17, 2, 1); STEPQ(18, 0, 2); STEPQ(19, 1, 0);
    STEPQ(20, 2, 1); STEPQ(21, 0, 2); STEPQ(22, 1, 0); STEPQ(23, 2, 1);
    STEPQ(24, 0, 2); STEPQ(25, 1, 0); STEPQ(26, 2, 1); STEPQ(27, 0, 2);
    STEPQ(28, 1, 0); STEPQ(29, 2, 1); STEPQ(30, 0, 2); STEPQ(31, 1, 0);

    if (more) {
      // outstanding VMEM (oldest->newest): stage(ti+1), 4 pack stores = 5;
      // in-order retirement => vmcnt(4) <=> stage(ti+1) arrived.
      asm volatile("s_waitcnt vmcnt(4)" ::: "memory");
      __builtin_amdgcn_sched_barrier(0);
    }
  }
}

// ---------------- scatter cid bytes to the per-pixel lane map ----------------
__global__ void k_scatter(const unsigned char* __restrict__ cidArr,
                          const int* __restrict__ idxC, const int* __restrict__ nvalid,
                          unsigned char* __restrict__ lanes, int cap) {
  const int b = blockIdx.y;
  const int n = nvalid[b];
  for (int j = blockIdx.x * blockDim.x + threadIdx.x; j < n; j += gridDim.x * blockDim.x) {
    lanes[(size_t)b * HW_ + idxC[(size_t)b * cap + j]] = cidArr[(size_t)b * HW_ + j];
  }
}

// ---------------- per-(b,h) segment sums over 33 lane bins ----------------
__global__ void k_rowsum(const unsigned char* __restrict__ lanes,
                         const float* __restrict__ offp, const float* __restrict__ zp,
                         float* __restrict__ cnt, float* __restrict__ sx,
                         float* __restrict__ sz) {
  const int bh = blockIdx.x;
  const int b = bh >> 9, h = bh & 511;
  __shared__ float sc[33], sxx[33], szz[33];
  const int t = threadIdx.x;
  if (t < 33) { sc[t] = 0.f; sxx[t] = 0.f; szz[t] = 0.f; }
  __syncthreads();
  const size_t base = (size_t)bh * W_;
  for (int x = t; x < W_; x += 256) {
    int ln = lanes[base + x];
    float o = offp[base + x];
    float sig = 1.0f / (1.0f + expf(-o));
    float xa = (float)x + sig;
    float zv = zp[base + x];
    atomicAdd(&sc[ln], 1.0f);
    atomicAdd(&sxx[ln], xa);
    atomicAdd(&szz[ln], zv);
  }
  __syncthreads();
  if (t >= 1 && t < 33) {
    size_t o = ((size_t)b * K_ + (t - 1)) * H_ + h;
    cnt[o] = sc[t]; sx[o] = sxx[t]; sz[o] = szz[t];
  }
}

// ---------------- validity + point assembly ----------------
__global__ void k_final(const float* __restrict__ cnt, const float* __restrict__ sx,
                        const float* __restrict__ sz, float* __restrict__ out) {
  const int bk = blockIdx.x;
  const int b = bk >> 5, k = bk & 31;
  const int h = threadIdx.x;
  const size_t o = (size_t)bk * H_ + h;
  float c = cnt[o];
  float sc_ = c, sn = (c > 0.f) ? 1.f : 0.f;
#pragma unroll
  for (int off = 32; off >= 1; off >>= 1) {
    sc_ += __shfl_down(sc_, off);
    sn += __shfl_down(sn, off);
  }
  __shared__ float rs[8], rn[8], tot[2];
  const int wid = h >> 6, lid = h & 63;
  if (lid == 0) { rs[wid] = sc_; rn[wid] = sn; }
  __syncthreads();
  if (h == 0) {
    float a = 0, bb = 0;
#pragma unroll
    for (int q = 0; q < 8; ++q) { a += rs[q]; bb += rn[q]; }
    tot[0] = a; tot[1] = bb;
  }
  __syncthreads();
  float size = tot[0], nrows = tot[1];
  bool valid = (c > 0.f) && (size >= 50.f) && (nrows >= 2.f);
  float mx = sx[o] / fmaxf(c, 1.f);
  float mz = sz[o] / fmaxf(c, 1.f);
  float xw = (512.0f - ((float)h + 0.5f)) * 0.2f;
  float yw = -(mx - 256.0f) * 0.2f;
  out[((size_t)(b * 3 + 0) * K_ + k) * H_ + h] = valid ? xw : 0.f;
  out[((size_t)(b * 3 + 1) * K_ + k) * H_ + h] = valid ? yw : 0.f;
  out[((size_t)(b * 3 + 2) * K_ + k) * H_ + h] = valid ? mz : 0.f;
  out[(size_t)B_ * 3 * K_ * H_ + (size_t)bk * H_ + h] = valid ? 1.f : 0.f;
}

extern "C" void kernel_launch(void* const* d_in, const int* in_sizes, int n_in,
                              void* d_out, int out_size, void* d_ws, size_t ws_size,
                              hipStream_t stream) {
  const float* seg  = (const float*)d_in[0];
  const float* emb  = (const float*)d_in[1];
  const float* offp = (const float*)d_in[2];
  const float* zp   = (const float*)d_in[3];
  float* out = (float*)d_out;
  char* ws = (char*)d_ws;

  const size_t lanesOff = 0;
  const size_t cntOff   = (size_t)B_ * HW_;
  const size_t sxOff    = cntOff + (size_t)B_ * K_ * H_ * 4;
  const size_t szOff    = sxOff  + (size_t)B_ * K_ * H_ * 4;
  const size_t nvOff    = szOff  + (size_t)B_ * K_ * H_ * 4;
  const size_t ccOff    = nvOff + 256;
  const size_t cbOff    = ccOff + 1024;
  const size_t cidOff   = cbOff + 1024;                      // u8 [B][HW_] = 2 MiB
  const size_t idxOff   = cidOff + (size_t)B_ * HW_;
  size_t avail = (ws_size > idxOff + 8192) ? (ws_size - idxOff - 8192) : 0;  // staging slack
  long long capLL = (long long)(avail / ((size_t)B_ * 36));  // 4B idx + 32B emb per entry
  if (capLL > (long long)HW_) capLL = HW_;
  if (capLL < 2) capLL = 2;
  capLL &= ~1LL;  // keep per-batch embC base 64B-aligned
  const int cap = (int)capLL;
  const size_t embOff = idxOff + (size_t)B_ * cap * 4;

  unsigned char* lanes = (unsigned char*)(ws + lanesOff);
  float* cnt = (float*)(ws + cntOff);
  float* sx  = (float*)(ws + sxOff);
  float* sz  = (float*)(ws + szOff);
  int* nvalid = (int*)(ws + nvOff);
  int* chunkCnt  = (int*)(ws + ccOff);
  int* chunkBase = (int*)(ws + cbOff);
  unsigned char* cidArr = (unsigned char*)(ws + cidOff);
  int* idxC   = (int*)(ws + idxOff);
  float* embC = (float*)(ws + embOff);

  k_count<<<B_ * CH_, 256, 0, stream>>>(seg, chunkCnt);
  k_scan<<<1, 128, 0, stream>>>(chunkCnt, chunkBase, nvalid, cap);
  k_fill<<<B_ * CH_, 256, 0, stream>>>(seg, emb, chunkBase, lanes, idxC, embC, cap);
  k_cluster<<<B_, 64, 0, stream>>>(embC, nvalid, cidArr, cap);
  k_scatter<<<dim3(64, B_), 256, 0, stream>>>(cidArr, idxC, nvalid, lanes, cap);
  k_rowsum<<<B_ * H_, 256, 0, stream>>>(lanes, offp, zp, cnt, sx, sz);
  k_final<<<B_ * K_, H_, 0, stream>>>(cnt, sx, sz, out);
}